// Round 1
// baseline (7879.924 us; speedup 1.0000x reference)
//
#include <hip/hip_runtime.h>
#include <hip/hip_bf16.h>
#include <math.h>

#define DIM 384
#define HEADS 12
#define HD 32
#define MLP_H 1536
#define BATCH 8
#define N1 256
#define N2 257
#define SCALE 0.17677669529663687f
#define TIME_SCALE 18.0f

// ------------------------------------------------------------------
// rel bias: rel[b,i,j,c] = sin_emb(1024*clip(d,-4,4))[k] @ wp[c,k] + bp[c]
// one thread per (b,i,j) pair, 32 outputs each
// ------------------------------------------------------------------
__global__ __launch_bounds__(256) void rel_kernel(
        const float* __restrict__ x0, const float* __restrict__ w1d,
        const float* __restrict__ b1d, const float* __restrict__ wp,
        const float* __restrict__ bp, float* __restrict__ rel) {
    __shared__ float swp[HD * HD];
    __shared__ float sbp[HD];
    __shared__ float sw1[8];
    __shared__ float sb1;
    __shared__ float sfreq[16];
    int tid = threadIdx.x;
    for (int i = tid; i < HD * HD; i += 256) swp[i] = wp[i];
    if (tid < HD) sbp[tid] = bp[tid];
    if (tid < 8) sw1[tid] = w1d[tid];
    if (tid == 0) sb1 = b1d[0];
    if (tid < 16) sfreq[tid] = expf(-(float)tid * 0.5756462732485114f); // ln(1e4)/16
    __syncthreads();

    int gid = blockIdx.x * 256 + tid;       // b*N1*N1 + i*N1 + j
    int j  = gid & (N1 - 1);
    int bi = gid >> 8;
    int i  = bi & (N1 - 1);
    int b  = bi >> 8;

    const float* pi = x0 + (size_t)(b * N1 + i) * 4;
    const float* pj = x0 + (size_t)(b * N1 + j) * 4;
    float dx = pi[0] - pj[0], dy = pi[1] - pj[1], dz = pi[2] - pj[2];
    float dt = pi[3] - pj[3] * TIME_SCALE;
    float dx2 = dx * dx, dy2 = dy * dy, dz2 = dz * dz, dt2 = dt * dt;
    float ds2 = dx2 + dy2 + dz2 - dt2;
    float d = copysignf(sqrtf(fabsf(ds2)), ds2);
    d += dx * sw1[0] + dy * sw1[1] + dz * sw1[2] + dt * sw1[3]
       + dx2 * sw1[4] + dy2 * sw1[5] + dz2 * sw1[6] + dt2 * sw1[7] + sb1;
    d = fminf(fmaxf(d, -4.f), 4.f) * 1024.f;

    float emb[32];
    #pragma unroll
    for (int k = 0; k < 16; k++) {
        float s, c;
        sincosf(d * sfreq[k], &s, &c);
        emb[k] = s; emb[16 + k] = c;
    }
    float* out = rel + (size_t)gid * HD;
    #pragma unroll 4
    for (int c = 0; c < HD; c++) {
        float a = sbp[c];
        #pragma unroll
        for (int k = 0; k < 32; k++) a += emb[k] * swp[c * 32 + k];
        out[c] = a;
    }
}

// ------------------------------------------------------------------
// LayerNorm: one block (128 thr) per row of 384
// ------------------------------------------------------------------
__global__ __launch_bounds__(128) void ln_kernel(
        const float* __restrict__ x, const float* __restrict__ g,
        const float* __restrict__ b, float* __restrict__ y) {
    int r = blockIdx.x;
    int t = threadIdx.x;
    const float* xr = x + (size_t)r * DIM;
    float v0 = xr[t], v1 = xr[t + 128], v2 = xr[t + 256];
    __shared__ float redm[2], redv[2];
    float s = v0 + v1 + v2;
    for (int o = 32; o; o >>= 1) s += __shfl_down(s, o, 64);
    int lane = t & 63, wid = t >> 6;
    if (!lane) redm[wid] = s;
    __syncthreads();
    float mean = (redm[0] + redm[1]) * (1.f / DIM);
    float d0 = v0 - mean, d1 = v1 - mean, d2 = v2 - mean;
    float s2 = d0 * d0 + d1 * d1 + d2 * d2;
    for (int o = 32; o; o >>= 1) s2 += __shfl_down(s2, o, 64);
    if (!lane) redv[wid] = s2;
    __syncthreads();
    float var = (redv[0] + redv[1]) * (1.f / DIM);
    float rs = rsqrtf(var + 1e-5f);
    float* yr = y + (size_t)r * DIM;
    yr[t]       = d0 * rs * g[t]       + b[t];
    yr[t + 128] = d1 * rs * g[t + 128] + b[t + 128];
    yr[t + 256] = d2 * rs * g[t + 256] + b[t + 256];
}

// ------------------------------------------------------------------
// GEMM: C[m,n] = act(A[m,:].W[n,:] + bias[n]); opt: C = resid + gvec*val
// A (M,K) row-major, W (N,K) row-major. 64x64x16 tiles, 4x4 per thread.
// ------------------------------------------------------------------
__global__ __launch_bounds__(256) void gemm_kernel(
        const float* __restrict__ A, const float* __restrict__ W,
        const float* __restrict__ bias, const float* __restrict__ resid,
        const float* __restrict__ gvec, float* __restrict__ C,
        int M, int Nn, int K, int do_gelu) {
    __shared__ float As[64][20];
    __shared__ float Ws[64][20];
    int tid = threadIdx.x;
    int n0 = blockIdx.x * 64;
    int m0 = blockIdx.y * 64;
    int tx = tid & 15, ty = tid >> 4;
    int lrow = tid >> 2, lcol = (tid & 3) * 4;

    float acc[4][4];
    #pragma unroll
    for (int a = 0; a < 4; a++)
        #pragma unroll
        for (int bb = 0; bb < 4; bb++) acc[a][bb] = 0.f;

    for (int k0 = 0; k0 < K; k0 += 16) {
        int am = m0 + lrow;
        float4 av = make_float4(0.f, 0.f, 0.f, 0.f);
        if (am < M) av = *(const float4*)(A + (size_t)am * K + k0 + lcol);
        As[lrow][lcol] = av.x; As[lrow][lcol + 1] = av.y;
        As[lrow][lcol + 2] = av.z; As[lrow][lcol + 3] = av.w;
        float4 wv = *(const float4*)(W + (size_t)(n0 + lrow) * K + k0 + lcol);
        Ws[lrow][lcol] = wv.x; Ws[lrow][lcol + 1] = wv.y;
        Ws[lrow][lcol + 2] = wv.z; Ws[lrow][lcol + 3] = wv.w;
        __syncthreads();
        #pragma unroll
        for (int k = 0; k < 16; k += 4) {
            float4 ra[4], rb[4];
            #pragma unroll
            for (int a = 0; a < 4; a++) ra[a] = *(const float4*)&As[ty + 16 * a][k];
            #pragma unroll
            for (int bb = 0; bb < 4; bb++) rb[bb] = *(const float4*)&Ws[tx + 16 * bb][k];
            #pragma unroll
            for (int a = 0; a < 4; a++)
                #pragma unroll
                for (int bb = 0; bb < 4; bb++)
                    acc[a][bb] += ra[a].x * rb[bb].x + ra[a].y * rb[bb].y
                                + ra[a].z * rb[bb].z + ra[a].w * rb[bb].w;
        }
        __syncthreads();
    }
    #pragma unroll
    for (int a = 0; a < 4; a++) {
        int m = m0 + ty + 16 * a;
        if (m >= M) continue;
        #pragma unroll
        for (int bb = 0; bb < 4; bb++) {
            int n = n0 + tx + 16 * bb;
            float v = acc[a][bb];
            if (bias) v += bias[n];
            if (do_gelu) v = 0.5f * v * (1.f + erff(v * 0.70710678118654752f));
            if (resid) {
                float gs = gvec ? gvec[n] : 1.f;
                v = resid[(size_t)m * Nn + n] + gs * v;
            }
            C[(size_t)m * Nn + n] = v;
        }
    }
}

// ------------------------------------------------------------------
// Attention: one block (256 thr) per (b,h,i). q,k,v in (B*Nseq, 384)
// layout (head h at cols h*32..). Optional rel (layer 0, phase 1).
// ------------------------------------------------------------------
__global__ __launch_bounds__(256) void attn_kernel(
        const float* __restrict__ qb, const float* __restrict__ kb,
        const float* __restrict__ vb, const float* __restrict__ relb,
        const float* __restrict__ maskv, float* __restrict__ ob,
        int Nseq, int use_rel) {
    int i = blockIdx.x, h = blockIdx.y, b = blockIdx.z;
    int tid = threadIdx.x;
    __shared__ float qs[HD];
    __shared__ float sc[272];
    __shared__ float red[4];
    __shared__ float redo[256];

    const size_t rowq = ((size_t)(b * Nseq) + i) * DIM + h * HD;
    if (tid < HD) qs[tid] = qb[rowq + tid] * SCALE;
    __syncthreads();

    float mi = maskv[b * Nseq + i];
    float lmax = -3.4e38f;
    for (int j = tid; j < Nseq; j += 256) {
        const float* kr = kb + ((size_t)(b * Nseq) + j) * DIM + h * HD;
        float s = 0.f;
        #pragma unroll
        for (int c = 0; c < HD; c++) s += qs[c] * kr[c];
        if (use_rel) {
            const float* rr = relb + (((size_t)(b * N1) + i) * N1 + j) * HD;
            #pragma unroll
            for (int c = 0; c < HD; c++) s += qs[c] * rr[c];
        }
        float mj = maskv[b * Nseq + j];
        float mn = fminf(mi, mj), mx = fmaxf(mi, mj);
        s += (mx < 0.f) ? 0.f : mn;
        sc[j] = s;
        lmax = fmaxf(lmax, s);
    }
    for (int o = 32; o; o >>= 1) lmax = fmaxf(lmax, __shfl_down(lmax, o, 64));
    int lane = tid & 63, wid = tid >> 6;
    if (!lane) red[wid] = lmax;
    __syncthreads();
    float mx4 = fmaxf(fmaxf(red[0], red[1]), fmaxf(red[2], red[3]));
    __syncthreads();

    float lsum = 0.f;
    for (int j = tid; j < Nseq; j += 256) {
        float e = expf(sc[j] - mx4);
        sc[j] = e;
        lsum += e;
    }
    for (int o = 32; o; o >>= 1) lsum += __shfl_down(lsum, o, 64);
    if (!lane) red[wid] = lsum;
    __syncthreads();
    float inv = 1.f / (red[0] + red[1] + red[2] + red[3]);

    int c = tid & 31, g = tid >> 5;   // 8 groups of 32
    float part = 0.f;
    for (int j = g; j < Nseq; j += 8) {
        float p = sc[j];
        part += p * vb[((size_t)(b * Nseq) + j) * DIM + h * HD + c];
        if (use_rel)
            part += p * relb[(((size_t)(b * N1) + i) * N1 + j) * HD + c];
    }
    redo[tid] = part;
    __syncthreads();
    if (tid < HD) {
        float o = 0.f;
        #pragma unroll
        for (int gg = 0; gg < 8; gg++) o += redo[gg * 32 + tid];
        ob[rowq + tid] = o * inv;
    }
}

// ------------------------------------------------------------------
// concat cls + build mask2
// ------------------------------------------------------------------
__global__ __launch_bounds__(256) void concat_kernel(
        const float* __restrict__ xa, const float* __restrict__ clsw,
        const float* __restrict__ mask, float* __restrict__ xb,
        float* __restrict__ m2) {
    int idx = blockIdx.x * 256 + threadIdx.x;
    const int total = BATCH * N2 * DIM;
    if (idx < total) {
        int c = idx % DIM;
        int tokb = idx / DIM;
        int p = tokb % N2, b = tokb / N2;
        xb[idx] = (p == 0) ? clsw[c] : xa[((size_t)(b * N1) + p - 1) * DIM + c];
    }
    if (idx < BATCH * N2) {
        int p = idx % N2, b = idx / N2;
        m2[idx] = (p == 0) ? 0.f : mask[b * N1 + p - 1];
    }
}

// ------------------------------------------------------------------
// head: out[b,o] = x[b,0,:].out_w[o,:] + out_b[o]; one wave per (b,o)
// ------------------------------------------------------------------
__global__ __launch_bounds__(64) void head_kernel(
        const float* __restrict__ xb, const float* __restrict__ ow,
        const float* __restrict__ obv, float* __restrict__ out) {
    int blk = blockIdx.x;
    int b = blk / 3, o = blk % 3;
    int lane = threadIdx.x;
    const float* xr = xb + (size_t)(b * N2) * DIM;
    const float* wr = ow + o * DIM;
    float s = 0.f;
    for (int c = lane; c < DIM; c += 64) s += xr[c] * wr[c];
    for (int off = 32; off; off >>= 1) s += __shfl_down(s, off, 64);
    if (!lane) out[blk] = s + obv[o];
}

// ------------------------------------------------------------------
extern "C" void kernel_launch(void* const* d_in, const int* in_sizes, int n_in,
                              void* d_out, int out_size, void* d_ws, size_t ws_size,
                              hipStream_t stream) {
    (void)in_sizes; (void)n_in; (void)out_size; (void)ws_size;
    const float* X       = (const float*)d_in[0];
    const float* X0      = (const float*)d_in[1];
    const float* MSK     = (const float*)d_in[2];
    const float* RW1     = (const float*)d_in[3];
    const float* RB1     = (const float*)d_in[4];
    const float* RWP     = (const float*)d_in[5];
    const float* RBP     = (const float*)d_in[6];
    const float* SW_LN1G = (const float*)d_in[7];
    const float* SW_LN1B = (const float*)d_in[8];
    const float* SW_LN2G = (const float*)d_in[9];
    const float* SW_LN2B = (const float*)d_in[10];
    const float* SW_WQ   = (const float*)d_in[11];
    const float* SW_WK   = (const float*)d_in[12];
    const float* SW_WV   = (const float*)d_in[13];
    const float* SW_WO   = (const float*)d_in[14];
    const float* SW_BO   = (const float*)d_in[15];
    const float* SW_W1   = (const float*)d_in[16];
    const float* SW_B1   = (const float*)d_in[17];
    const float* SW_W2   = (const float*)d_in[18];
    const float* SW_B2   = (const float*)d_in[19];
    const float* BL_LN1G = (const float*)d_in[20];
    const float* BL_LN1B = (const float*)d_in[21];
    const float* BL_LN2G = (const float*)d_in[22];
    const float* BL_LN2B = (const float*)d_in[23];
    const float* BL_WQ   = (const float*)d_in[24];
    const float* BL_WK   = (const float*)d_in[25];
    const float* BL_WV   = (const float*)d_in[26];
    const float* BL_WO   = (const float*)d_in[27];
    const float* BL_BO   = (const float*)d_in[28];
    const float* BL_W1   = (const float*)d_in[29];
    const float* BL_B1   = (const float*)d_in[30];
    const float* BL_W2   = (const float*)d_in[31];
    const float* BL_B2   = (const float*)d_in[32];
    const float* BL_G1   = (const float*)d_in[33];
    const float* BL_G2   = (const float*)d_in[34];
    const float* CLSW    = (const float*)d_in[35];
    const float* OUTW    = (const float*)d_in[36];
    const float* OUTB    = (const float*)d_in[37];

    const int T1 = BATCH * N1;   // 2048
    const int T2 = BATCH * N2;   // 2056
    const size_t ROWS = (size_t)T2 * DIM;        // 789504 (max rows buffer)
    const size_t RELSZ = (size_t)BATCH * N1 * N1 * HD;

    float* ws  = (float*)d_ws;
    float* rel = ws;
    float* xa  = rel + RELSZ;
    float* xb  = xa + ROWS;
    float* xn  = xb + ROWS;
    float* qb  = xn + ROWS;
    float* kb  = qb + ROWS;
    float* vb  = kb + ROWS;
    float* ab  = vb + ROWS;
    float* hb  = ab + ROWS;
    float* m2  = hb + (size_t)T2 * MLP_H;

    rel_kernel<<<BATCH * N1 * N1 / 256, 256, 0, stream>>>(X0, RW1, RB1, RWP, RBP, rel);
    hipMemcpyAsync(xa, X, sizeof(float) * T1 * DIM, hipMemcpyDeviceToDevice, stream);

    // ---------------- phase 1: sw layers (N=256) ----------------
    dim3 gP1(DIM / 64, T1 / 64);          // (6,32)
    dim3 gM1(MLP_H / 64, T1 / 64);        // (24,32)
    for (int l = 0; l < 4; l++) {
        const float* wq = SW_WQ + (size_t)l * DIM * DIM;
        const float* wk = SW_WK + (size_t)l * DIM * DIM;
        const float* wv = SW_WV + (size_t)l * DIM * DIM;
        const float* wo = SW_WO + (size_t)l * DIM * DIM;
        const float* bo = SW_BO + (size_t)l * DIM;
        const float* w1 = SW_W1 + (size_t)l * MLP_H * DIM;
        const float* b1 = SW_B1 + (size_t)l * MLP_H;
        const float* w2 = SW_W2 + (size_t)l * DIM * MLP_H;
        const float* b2 = SW_B2 + (size_t)l * DIM;

        ln_kernel<<<T1, 128, 0, stream>>>(xa, SW_LN1G + l * DIM, SW_LN1B + l * DIM, xn);
        gemm_kernel<<<gP1, 256, 0, stream>>>(xn, wq, nullptr, nullptr, nullptr, qb, T1, DIM, DIM, 0);
        gemm_kernel<<<gP1, 256, 0, stream>>>(xn, wk, nullptr, nullptr, nullptr, kb, T1, DIM, DIM, 0);
        gemm_kernel<<<gP1, 256, 0, stream>>>(xn, wv, nullptr, nullptr, nullptr, vb, T1, DIM, DIM, 0);
        attn_kernel<<<dim3(N1, HEADS, BATCH), 256, 0, stream>>>(
            qb, kb, vb, rel, MSK, ab, N1, (l == 0) ? 1 : 0);
        gemm_kernel<<<gP1, 256, 0, stream>>>(ab, wo, bo, xa, nullptr, xa, T1, DIM, DIM, 0);
        ln_kernel<<<T1, 128, 0, stream>>>(xa, SW_LN2G + l * DIM, SW_LN2B + l * DIM, xn);
        gemm_kernel<<<gM1, 256, 0, stream>>>(xn, w1, b1, nullptr, nullptr, hb, T1, MLP_H, DIM, 1);
        gemm_kernel<<<gP1, 256, 0, stream>>>(hb, w2, b2, xa, nullptr, xa, T1, DIM, MLP_H, 0);
    }

    // ---------------- concat cls ----------------
    concat_kernel<<<(BATCH * N2 * DIM + 255) / 256, 256, 0, stream>>>(xa, CLSW, MSK, xb, m2);

    // ---------------- phase 2: bl layers (N=257) ----------------
    int MB2 = (T2 + 63) / 64;             // 33
    dim3 gP2(DIM / 64, MB2);
    dim3 gM2(MLP_H / 64, MB2);
    for (int l = 0; l < 12; l++) {
        const float* wq = BL_WQ + (size_t)l * DIM * DIM;
        const float* wk = BL_WK + (size_t)l * DIM * DIM;
        const float* wv = BL_WV + (size_t)l * DIM * DIM;
        const float* wo = BL_WO + (size_t)l * DIM * DIM;
        const float* bo = BL_BO + (size_t)l * DIM;
        const float* w1 = BL_W1 + (size_t)l * MLP_H * DIM;
        const float* b1 = BL_B1 + (size_t)l * MLP_H;
        const float* w2 = BL_W2 + (size_t)l * DIM * MLP_H;
        const float* b2 = BL_B2 + (size_t)l * DIM;
        const float* g1 = BL_G1 + (size_t)l * DIM;
        const float* g2 = BL_G2 + (size_t)l * DIM;

        ln_kernel<<<T2, 128, 0, stream>>>(xb, BL_LN1G + l * DIM, BL_LN1B + l * DIM, xn);
        gemm_kernel<<<gP2, 256, 0, stream>>>(xn, wq, nullptr, nullptr, nullptr, qb, T2, DIM, DIM, 0);
        gemm_kernel<<<gP2, 256, 0, stream>>>(xn, wk, nullptr, nullptr, nullptr, kb, T2, DIM, DIM, 0);
        gemm_kernel<<<gP2, 256, 0, stream>>>(xn, wv, nullptr, nullptr, nullptr, vb, T2, DIM, DIM, 0);
        attn_kernel<<<dim3(N2, HEADS, BATCH), 256, 0, stream>>>(
            qb, kb, vb, nullptr, m2, ab, N2, 0);
        gemm_kernel<<<gP2, 256, 0, stream>>>(ab, wo, bo, xb, g1, xb, T2, DIM, DIM, 0);
        ln_kernel<<<T2, 128, 0, stream>>>(xb, BL_LN2G + l * DIM, BL_LN2B + l * DIM, xn);
        gemm_kernel<<<gM2, 256, 0, stream>>>(xn, w1, b1, nullptr, nullptr, hb, T2, MLP_H, DIM, 1);
        gemm_kernel<<<gP2, 256, 0, stream>>>(hb, w2, b2, xb, g2, xb, T2, DIM, MLP_H, 0);
    }

    // ---------------- head ----------------
    head_kernel<<<BATCH * 3, 64, 0, stream>>>(xb, OUTW, OUTB, (float*)d_out);
}

// Round 2
// 5352.142 us; speedup vs baseline: 1.4723x; 1.4723x over previous
//
#include <hip/hip_runtime.h>
#include <hip/hip_bf16.h>
#include <math.h>

#define DIM 384
#define HEADS 12
#define HD 32
#define MLP_H 1536
#define BATCH 8
#define N1 256
#define N2 257
#define SCALE 0.17677669529663687f
#define TIME_SCALE 18.0f

// ------------------------------------------------------------------
// rel bias: rel[b,i,j,c] = sin_emb(1024*clip(d,-4,4))[k] @ wp[c,k] + bp[c]
// ------------------------------------------------------------------
__global__ __launch_bounds__(256) void rel_kernel(
        const float* __restrict__ x0, const float* __restrict__ w1d,
        const float* __restrict__ b1d, const float* __restrict__ wp,
        const float* __restrict__ bp, float* __restrict__ rel) {
    __shared__ float swp[HD * HD];
    __shared__ float sbp[HD];
    __shared__ float sw1[8];
    __shared__ float sb1;
    __shared__ float sfreq[16];
    int tid = threadIdx.x;
    for (int i = tid; i < HD * HD; i += 256) swp[i] = wp[i];
    if (tid < HD) sbp[tid] = bp[tid];
    if (tid < 8) sw1[tid] = w1d[tid];
    if (tid == 0) sb1 = b1d[0];
    if (tid < 16) sfreq[tid] = expf(-(float)tid * 0.5756462732485114f);
    __syncthreads();

    int gid = blockIdx.x * 256 + tid;
    int j  = gid & (N1 - 1);
    int bi = gid >> 8;
    int i  = bi & (N1 - 1);
    int b  = bi >> 8;

    const float* pi = x0 + (size_t)(b * N1 + i) * 4;
    const float* pj = x0 + (size_t)(b * N1 + j) * 4;
    float dx = pi[0] - pj[0], dy = pi[1] - pj[1], dz = pi[2] - pj[2];
    float dt = pi[3] - pj[3] * TIME_SCALE;
    float dx2 = dx * dx, dy2 = dy * dy, dz2 = dz * dz, dt2 = dt * dt;
    float ds2 = dx2 + dy2 + dz2 - dt2;
    float d = copysignf(sqrtf(fabsf(ds2)), ds2);
    d += dx * sw1[0] + dy * sw1[1] + dz * sw1[2] + dt * sw1[3]
       + dx2 * sw1[4] + dy2 * sw1[5] + dz2 * sw1[6] + dt2 * sw1[7] + sb1;
    d = fminf(fmaxf(d, -4.f), 4.f) * 1024.f;

    float emb[32];
    #pragma unroll
    for (int k = 0; k < 16; k++) {
        float s, c;
        sincosf(d * sfreq[k], &s, &c);
        emb[k] = s; emb[16 + k] = c;
    }
    float* out = rel + (size_t)gid * HD;
    #pragma unroll 4
    for (int c = 0; c < HD; c++) {
        float a = sbp[c];
        #pragma unroll
        for (int k = 0; k < 32; k++) a += emb[k] * swp[c * 32 + k];
        out[c] = a;
    }
}

// ------------------------------------------------------------------
// LayerNorm
// ------------------------------------------------------------------
__global__ __launch_bounds__(128) void ln_kernel(
        const float* __restrict__ x, const float* __restrict__ g,
        const float* __restrict__ b, float* __restrict__ y) {
    int r = blockIdx.x;
    int t = threadIdx.x;
    const float* xr = x + (size_t)r * DIM;
    float v0 = xr[t], v1 = xr[t + 128], v2 = xr[t + 256];
    __shared__ float redm[2], redv[2];
    float s = v0 + v1 + v2;
    for (int o = 32; o; o >>= 1) s += __shfl_down(s, o, 64);
    int lane = t & 63, wid = t >> 6;
    if (!lane) redm[wid] = s;
    __syncthreads();
    float mean = (redm[0] + redm[1]) * (1.f / DIM);
    float d0 = v0 - mean, d1 = v1 - mean, d2 = v2 - mean;
    float s2 = d0 * d0 + d1 * d1 + d2 * d2;
    for (int o = 32; o; o >>= 1) s2 += __shfl_down(s2, o, 64);
    if (!lane) redv[wid] = s2;
    __syncthreads();
    float var = (redv[0] + redv[1]) * (1.f / DIM);
    float rs = rsqrtf(var + 1e-5f);
    float* yr = y + (size_t)r * DIM;
    yr[t]       = d0 * rs * g[t]       + b[t];
    yr[t + 128] = d1 * rs * g[t + 128] + b[t + 128];
    yr[t + 256] = d2 * rs * g[t + 256] + b[t + 256];
}

// ------------------------------------------------------------------
// Generic GEMM (64x64 tile): C = act(A.W^T + bias), opt resid+gate
// ------------------------------------------------------------------
__global__ __launch_bounds__(256) void gemm_kernel(
        const float* __restrict__ A, const float* __restrict__ W,
        const float* __restrict__ bias, const float* __restrict__ resid,
        const float* __restrict__ gvec, float* __restrict__ C,
        int M, int Nn, int K, int do_gelu) {
    __shared__ float As[64][20];
    __shared__ float Ws[64][20];
    int tid = threadIdx.x;
    int n0 = blockIdx.x * 64;
    int m0 = blockIdx.y * 64;
    int tx = tid & 15, ty = tid >> 4;
    int lrow = tid >> 2, lcol = (tid & 3) * 4;

    float acc[4][4];
    #pragma unroll
    for (int a = 0; a < 4; a++)
        #pragma unroll
        for (int bb = 0; bb < 4; bb++) acc[a][bb] = 0.f;

    for (int k0 = 0; k0 < K; k0 += 16) {
        int am = m0 + lrow;
        float4 av = make_float4(0.f, 0.f, 0.f, 0.f);
        if (am < M) av = *(const float4*)(A + (size_t)am * K + k0 + lcol);
        As[lrow][lcol] = av.x; As[lrow][lcol + 1] = av.y;
        As[lrow][lcol + 2] = av.z; As[lrow][lcol + 3] = av.w;
        float4 wv = *(const float4*)(W + (size_t)(n0 + lrow) * K + k0 + lcol);
        Ws[lrow][lcol] = wv.x; Ws[lrow][lcol + 1] = wv.y;
        Ws[lrow][lcol + 2] = wv.z; Ws[lrow][lcol + 3] = wv.w;
        __syncthreads();
        #pragma unroll
        for (int k = 0; k < 16; k += 4) {
            float4 ra[4], rb[4];
            #pragma unroll
            for (int a = 0; a < 4; a++) ra[a] = *(const float4*)&As[ty + 16 * a][k];
            #pragma unroll
            for (int bb = 0; bb < 4; bb++) rb[bb] = *(const float4*)&Ws[tx + 16 * bb][k];
            #pragma unroll
            for (int a = 0; a < 4; a++)
                #pragma unroll
                for (int bb = 0; bb < 4; bb++)
                    acc[a][bb] += ra[a].x * rb[bb].x + ra[a].y * rb[bb].y
                                + ra[a].z * rb[bb].z + ra[a].w * rb[bb].w;
        }
        __syncthreads();
    }
    #pragma unroll
    for (int a = 0; a < 4; a++) {
        int m = m0 + ty + 16 * a;
        if (m >= M) continue;
        #pragma unroll
        for (int bb = 0; bb < 4; bb++) {
            int n = n0 + tx + 16 * bb;
            float v = acc[a][bb];
            if (bias) v += bias[n];
            if (do_gelu) v = 0.5f * v * (1.f + erff(v * 0.70710678118654752f));
            if (resid) {
                float gs = gvec ? gvec[n] : 1.f;
                v = resid[(size_t)m * Nn + n] + gs * v;
            }
            C[(size_t)m * Nn + n] = v;
        }
    }
}

// ------------------------------------------------------------------
// Fused QKV projection: same A, three weight matrices (384x384 each)
// ------------------------------------------------------------------
__global__ __launch_bounds__(256) void gemm_qkv_kernel(
        const float* __restrict__ A, const float* __restrict__ Wq,
        const float* __restrict__ Wk, const float* __restrict__ Wv,
        float* __restrict__ Oq, float* __restrict__ Ok, float* __restrict__ Ov,
        int M) {
    __shared__ float As[64][20];
    __shared__ float Ws[64][20];
    int tid = threadIdx.x;
    int nb = blockIdx.x;                 // 0..17
    int which = nb / 6;
    int n0 = (nb % 6) * 64;
    const float* W = (which == 0) ? Wq : (which == 1) ? Wk : Wv;
    float* C = (which == 0) ? Oq : (which == 1) ? Ok : Ov;
    int m0 = blockIdx.y * 64;
    int tx = tid & 15, ty = tid >> 4;
    int lrow = tid >> 2, lcol = (tid & 3) * 4;

    float acc[4][4];
    #pragma unroll
    for (int a = 0; a < 4; a++)
        #pragma unroll
        for (int bb = 0; bb < 4; bb++) acc[a][bb] = 0.f;

    for (int k0 = 0; k0 < DIM; k0 += 16) {
        int am = m0 + lrow;
        float4 av = make_float4(0.f, 0.f, 0.f, 0.f);
        if (am < M) av = *(const float4*)(A + (size_t)am * DIM + k0 + lcol);
        As[lrow][lcol] = av.x; As[lrow][lcol + 1] = av.y;
        As[lrow][lcol + 2] = av.z; As[lrow][lcol + 3] = av.w;
        float4 wv = *(const float4*)(W + (size_t)(n0 + lrow) * DIM + k0 + lcol);
        Ws[lrow][lcol] = wv.x; Ws[lrow][lcol + 1] = wv.y;
        Ws[lrow][lcol + 2] = wv.z; Ws[lrow][lcol + 3] = wv.w;
        __syncthreads();
        #pragma unroll
        for (int k = 0; k < 16; k += 4) {
            float4 ra[4], rb[4];
            #pragma unroll
            for (int a = 0; a < 4; a++) ra[a] = *(const float4*)&As[ty + 16 * a][k];
            #pragma unroll
            for (int bb = 0; bb < 4; bb++) rb[bb] = *(const float4*)&Ws[tx + 16 * bb][k];
            #pragma unroll
            for (int a = 0; a < 4; a++)
                #pragma unroll
                for (int bb = 0; bb < 4; bb++)
                    acc[a][bb] += ra[a].x * rb[bb].x + ra[a].y * rb[bb].y
                                + ra[a].z * rb[bb].z + ra[a].w * rb[bb].w;
        }
        __syncthreads();
    }
    #pragma unroll
    for (int a = 0; a < 4; a++) {
        int m = m0 + ty + 16 * a;
        if (m >= M) continue;
        #pragma unroll
        for (int bb = 0; bb < 4; bb++) {
            int n = n0 + tx + 16 * bb;
            C[(size_t)m * DIM + n] = acc[a][bb];
        }
    }
}

// ------------------------------------------------------------------
// Attention v2: block = (b, h, 16-query chunk), 256 threads (4 waves).
// K staged transposed in LDS (pitch 260), scores to LDS, then V staged
// row-major (pitch 33), softmax + PV via in-wave role switch.
// Nseq in {256, 257}; tail column j=256 handled by split reduction.
// ------------------------------------------------------------------
#define KVP 260
#define VP 33
__global__ __launch_bounds__(256) void attn_kernel(
        const float* __restrict__ qb, const float* __restrict__ kb,
        const float* __restrict__ vb, const float* __restrict__ relb,
        const float* __restrict__ maskv, float* __restrict__ ob,
        int Nseq, int use_rel) {
    __shared__ float kvbuf[8580];     // max(32*260, 260*33)
    __shared__ float sc[16][260];
    __shared__ float qs4[32][16];
    __shared__ float qsT[16][32];
    __shared__ float ms[272];

    int tid = threadIdx.x;
    int w = tid >> 6, l = tid & 63;
    int chunk = blockIdx.x, h = blockIdx.y, b = blockIdx.z;
    int i0 = chunk * 16;
    size_t baseBH = (size_t)(b * Nseq) * DIM + h * HD;

    // ---- stage mask (padded with 0) ----
    for (int j = tid; j < 272; j += 256)
        ms[j] = (j < Nseq) ? maskv[b * Nseq + j] : 0.f;

    // ---- init sc tail columns ----
    for (int t = tid; t < 64; t += 256)
        sc[t >> 2][256 + (t & 3)] = -3.0e38f;

    // ---- stage q (both layouts) ----
    for (int t = tid; t < 512; t += 256) {
        int qq = t >> 5, c = t & 31;
        int i = i0 + qq;
        float v = 0.f;
        if (i < Nseq) v = qb[baseBH + (size_t)i * DIM + c] * SCALE;
        qs4[c][qq] = v;
        qsT[qq][c] = v;
    }

    // ---- stage K transposed: kvbuf[c*KVP + j] ----
    {
        int q4 = tid >> 5, r = tid & 31;
        for (int j = r; j < Nseq; j += 32) {
            float4 kvv = *(const float4*)(kb + baseBH + (size_t)j * DIM + q4 * 4);
            kvbuf[(4 * q4 + 0) * KVP + j] = kvv.x;
            kvbuf[(4 * q4 + 1) * KVP + j] = kvv.y;
            kvbuf[(4 * q4 + 2) * KVP + j] = kvv.z;
            kvbuf[(4 * q4 + 3) * KVP + j] = kvv.w;
        }
        for (int t = tid; t < 128; t += 256) {
            int cc = t >> 2, jj = 256 + (t & 3);
            if (jj >= Nseq) kvbuf[cc * KVP + jj] = 0.f;
        }
    }
    __syncthreads();

    // ---- scores: wave w handles queries qq=4w..4w+3, lane l -> j=4l..4l+3
    {
        float s[4][4];
        #pragma unroll
        for (int q = 0; q < 4; q++)
            #pragma unroll
            for (int t = 0; t < 4; t++) s[q][t] = 0.f;
        int j0 = 4 * l;
        #pragma unroll 8
        for (int c = 0; c < 32; c++) {
            float4 kq = *(const float4*)&kvbuf[c * KVP + j0];
            float4 q4 = *(const float4*)&qs4[c][4 * w];
            s[0][0] += q4.x * kq.x; s[0][1] += q4.x * kq.y; s[0][2] += q4.x * kq.z; s[0][3] += q4.x * kq.w;
            s[1][0] += q4.y * kq.x; s[1][1] += q4.y * kq.y; s[1][2] += q4.y * kq.z; s[1][3] += q4.y * kq.w;
            s[2][0] += q4.z * kq.x; s[2][1] += q4.z * kq.y; s[2][2] += q4.z * kq.z; s[2][3] += q4.z * kq.w;
            s[3][0] += q4.w * kq.x; s[3][1] += q4.w * kq.y; s[3][2] += q4.w * kq.z; s[3][3] += q4.w * kq.w;
        }
        if (use_rel) {                      // Nseq == 256 here
            #pragma unroll
            for (int q = 0; q < 4; q++) {
                int i = i0 + 4 * w + q;
                float qr[32];
                #pragma unroll
                for (int c4 = 0; c4 < 8; c4++) {
                    float4 t4 = *(const float4*)&qsT[4 * w + q][c4 * 4];
                    qr[4 * c4] = t4.x; qr[4 * c4 + 1] = t4.y;
                    qr[4 * c4 + 2] = t4.z; qr[4 * c4 + 3] = t4.w;
                }
                const float* rbase = relb + (((size_t)b * N1 + i) * N1 + j0) * HD;
                #pragma unroll
                for (int jj = 0; jj < 4; jj++) {
                    float a = 0.f;
                    #pragma unroll
                    for (int c4 = 0; c4 < 8; c4++) {
                        float4 rv = *(const float4*)(rbase + jj * HD + c4 * 4);
                        a += qr[4 * c4] * rv.x + qr[4 * c4 + 1] * rv.y
                           + qr[4 * c4 + 2] * rv.z + qr[4 * c4 + 3] * rv.w;
                    }
                    s[q][jj] += a;
                }
            }
        }
        // mask bias + write scores
        #pragma unroll
        for (int q = 0; q < 4; q++) {
            int i = i0 + 4 * w + q;
            float mi = ms[i];
            float4 o4;
            float mj, mn, mx;
            mj = ms[j0 + 0]; mn = fminf(mi, mj); mx = fmaxf(mi, mj);
            o4.x = s[q][0] + ((mx < 0.f) ? 0.f : mn);
            mj = ms[j0 + 1]; mn = fminf(mi, mj); mx = fmaxf(mi, mj);
            o4.y = s[q][1] + ((mx < 0.f) ? 0.f : mn);
            mj = ms[j0 + 2]; mn = fminf(mi, mj); mx = fmaxf(mi, mj);
            o4.z = s[q][2] + ((mx < 0.f) ? 0.f : mn);
            mj = ms[j0 + 3]; mn = fminf(mi, mj); mx = fmaxf(mi, mj);
            o4.w = s[q][3] + ((mx < 0.f) ? 0.f : mn);
            *(float4*)&sc[4 * w + q][j0] = o4;
        }
        // tail column j = 256 (Nseq == 257): split reduction over c
        if (Nseq > 256) {
            int c = l & 31, h2 = l >> 5;
            float k256 = kvbuf[c * KVP + 256];
            float pa = qs4[c][4 * w + 2 * h2]     * k256;
            float pb = qs4[c][4 * w + 2 * h2 + 1] * k256;
            #pragma unroll
            for (int o = 16; o; o >>= 1) {
                pa += __shfl_xor(pa, o, 32);
                pb += __shfl_xor(pb, o, 32);
            }
            if ((l & 31) == 0) {
                int qa = 4 * w + 2 * h2, ia = i0 + qa;
                float mj = ms[256];
                float mia = ms[ia], mib = ms[ia + 1];
                sc[qa][256]     = pa + ((fmaxf(mia, mj) < 0.f) ? 0.f : fminf(mia, mj));
                sc[qa + 1][256] = pb + ((fmaxf(mib, mj) < 0.f) ? 0.f : fminf(mib, mj));
            }
        }
    }
    __syncthreads();

    // ---- stage V row-major: kvbuf[j*VP + c] ----
    {
        int r = tid >> 3, q4 = tid & 7;
        for (int j = r; j < Nseq; j += 32) {
            float4 vv = *(const float4*)(vb + baseBH + (size_t)j * DIM + q4 * 4);
            kvbuf[j * VP + 4 * q4 + 0] = vv.x;
            kvbuf[j * VP + 4 * q4 + 1] = vv.y;
            kvbuf[j * VP + 4 * q4 + 2] = vv.z;
            kvbuf[j * VP + 4 * q4 + 3] = vv.w;
        }
        for (int t = tid; t < 132; t += 256) {
            int row = 256 + t / VP, cc = t % VP;
            if (row < 260 && row >= Nseq) kvbuf[row * VP + cc] = 0.f;
        }
    }
    __syncthreads();

    // ---- softmax (per wave, per query) ----
    float inv[4];
    #pragma unroll
    for (int q = 0; q < 4; q++) {
        int qq = 4 * w + q;
        float4 sv = *(const float4*)&sc[qq][4 * l];
        float lm = fmaxf(fmaxf(sv.x, sv.y), fmaxf(sv.z, sv.w));
        float s256 = -3.0e38f;
        if (Nseq > 256) s256 = sc[qq][256];
        lm = fmaxf(lm, s256);
        #pragma unroll
        for (int o = 32; o; o >>= 1) lm = fmaxf(lm, __shfl_xor(lm, o, 64));
        float4 ev;
        ev.x = expf(sv.x - lm); ev.y = expf(sv.y - lm);
        ev.z = expf(sv.z - lm); ev.w = expf(sv.w - lm);
        float ls = ev.x + ev.y + ev.z + ev.w;
        #pragma unroll
        for (int o = 32; o; o >>= 1) ls += __shfl_xor(ls, o, 64);
        if (Nseq > 256) {
            float e256 = expf(s256 - lm);
            ls += e256;
            if (l == 0) {
                float4 t4; t4.x = e256; t4.y = 0.f; t4.z = 0.f; t4.w = 0.f;
                *(float4*)&sc[qq][256] = t4;
            }
        }
        *(float4*)&sc[qq][4 * l] = ev;
        inv[q] = 1.f / ls;
    }

    // ---- PV: role switch, lane = (c, h2); j interleaved quads ----
    {
        int c = l & 31, h2 = l >> 5;
        float acc[4] = {0.f, 0.f, 0.f, 0.f};
        int JMAX = (Nseq > 256) ? 260 : 256;
        for (int j0 = 4 * h2; j0 < JMAX; j0 += 8) {
            float v0 = kvbuf[(j0 + 0) * VP + c];
            float v1 = kvbuf[(j0 + 1) * VP + c];
            float v2 = kvbuf[(j0 + 2) * VP + c];
            float v3 = kvbuf[(j0 + 3) * VP + c];
            #pragma unroll
            for (int q = 0; q < 4; q++) {
                float4 pv = *(const float4*)&sc[4 * w + q][j0];
                acc[q] += pv.x * v0 + pv.y * v1 + pv.z * v2 + pv.w * v3;
                if (use_rel) {
                    int i = i0 + 4 * w + q;
                    const float* rr = relb + (((size_t)b * N1 + i) * N1 + j0) * HD + c;
                    acc[q] += pv.x * rr[0] + pv.y * rr[HD] + pv.z * rr[2 * HD] + pv.w * rr[3 * HD];
                }
            }
        }
        #pragma unroll
        for (int q = 0; q < 4; q++) {
            float t = __shfl_down(acc[q], 32, 64);
            acc[q] += t;
        }
        if (l < 32) {
            #pragma unroll
            for (int q = 0; q < 4; q++) {
                int i = i0 + 4 * w + q;
                if (i < Nseq) ob[baseBH + (size_t)i * DIM + c] = acc[q] * inv[q];
            }
        }
    }
}

// ------------------------------------------------------------------
__global__ __launch_bounds__(256) void concat_kernel(
        const float* __restrict__ xa, const float* __restrict__ clsw,
        const float* __restrict__ mask, float* __restrict__ xb,
        float* __restrict__ m2) {
    int idx = blockIdx.x * 256 + threadIdx.x;
    const int total = BATCH * N2 * DIM;
    if (idx < total) {
        int c = idx % DIM;
        int tokb = idx / DIM;
        int p = tokb % N2, b = tokb / N2;
        xb[idx] = (p == 0) ? clsw[c] : xa[((size_t)(b * N1) + p - 1) * DIM + c];
    }
    if (idx < BATCH * N2) {
        int p = idx % N2, b = idx / N2;
        m2[idx] = (p == 0) ? 0.f : mask[b * N1 + p - 1];
    }
}

__global__ __launch_bounds__(64) void head_kernel(
        const float* __restrict__ xb, const float* __restrict__ ow,
        const float* __restrict__ obv, float* __restrict__ out) {
    int blk = blockIdx.x;
    int b = blk / 3, o = blk % 3;
    int lane = threadIdx.x;
    const float* xr = xb + (size_t)(b * N2) * DIM;
    const float* wr = ow + o * DIM;
    float s = 0.f;
    for (int c = lane; c < DIM; c += 64) s += xr[c] * wr[c];
    for (int off = 32; off; off >>= 1) s += __shfl_down(s, off, 64);
    if (!lane) out[blk] = s + obv[o];
}

// ------------------------------------------------------------------
extern "C" void kernel_launch(void* const* d_in, const int* in_sizes, int n_in,
                              void* d_out, int out_size, void* d_ws, size_t ws_size,
                              hipStream_t stream) {
    (void)in_sizes; (void)n_in; (void)out_size; (void)ws_size;
    const float* X       = (const float*)d_in[0];
    const float* X0      = (const float*)d_in[1];
    const float* MSK     = (const float*)d_in[2];
    const float* RW1     = (const float*)d_in[3];
    const float* RB1     = (const float*)d_in[4];
    const float* RWP     = (const float*)d_in[5];
    const float* RBP     = (const float*)d_in[6];
    const float* SW_LN1G = (const float*)d_in[7];
    const float* SW_LN1B = (const float*)d_in[8];
    const float* SW_LN2G = (const float*)d_in[9];
    const float* SW_LN2B = (const float*)d_in[10];
    const float* SW_WQ   = (const float*)d_in[11];
    const float* SW_WK   = (const float*)d_in[12];
    const float* SW_WV   = (const float*)d_in[13];
    const float* SW_WO   = (const float*)d_in[14];
    const float* SW_BO   = (const float*)d_in[15];
    const float* SW_W1   = (const float*)d_in[16];
    const float* SW_B1   = (const float*)d_in[17];
    const float* SW_W2   = (const float*)d_in[18];
    const float* SW_B2   = (const float*)d_in[19];
    const float* BL_LN1G = (const float*)d_in[20];
    const float* BL_LN1B = (const float*)d_in[21];
    const float* BL_LN2G = (const float*)d_in[22];
    const float* BL_LN2B = (const float*)d_in[23];
    const float* BL_WQ   = (const float*)d_in[24];
    const float* BL_WK   = (const float*)d_in[25];
    const float* BL_WV   = (const float*)d_in[26];
    const float* BL_WO   = (const float*)d_in[27];
    const float* BL_BO   = (const float*)d_in[28];
    const float* BL_W1   = (const float*)d_in[29];
    const float* BL_B1   = (const float*)d_in[30];
    const float* BL_W2   = (const float*)d_in[31];
    const float* BL_B2   = (const float*)d_in[32];
    const float* BL_G1   = (const float*)d_in[33];
    const float* BL_G2   = (const float*)d_in[34];
    const float* CLSW    = (const float*)d_in[35];
    const float* OUTW    = (const float*)d_in[36];
    const float* OUTB    = (const float*)d_in[37];

    const int T1 = BATCH * N1;   // 2048
    const int T2 = BATCH * N2;   // 2056
    const size_t ROWS = (size_t)T2 * DIM;
    const size_t RELSZ = (size_t)BATCH * N1 * N1 * HD;

    float* ws  = (float*)d_ws;
    float* rel = ws;
    float* xa  = rel + RELSZ;
    float* xb  = xa + ROWS;
    float* xn  = xb + ROWS;
    float* qb  = xn + ROWS;
    float* kb  = qb + ROWS;
    float* vb  = kb + ROWS;
    float* ab  = vb + ROWS;
    float* hb  = ab + ROWS;
    float* m2  = hb + (size_t)T2 * MLP_H;

    rel_kernel<<<BATCH * N1 * N1 / 256, 256, 0, stream>>>(X0, RW1, RB1, RWP, RBP, rel);
    hipMemcpyAsync(xa, X, sizeof(float) * T1 * DIM, hipMemcpyDeviceToDevice, stream);

    // ---------------- phase 1: sw layers (N=256) ----------------
    dim3 gP1(DIM / 64, T1 / 64);
    dim3 gQ1(18, T1 / 64);
    dim3 gM1(MLP_H / 64, T1 / 64);
    dim3 gA1((N1 + 15) / 16, HEADS, BATCH);
    for (int l = 0; l < 4; l++) {
        const float* wq = SW_WQ + (size_t)l * DIM * DIM;
        const float* wk = SW_WK + (size_t)l * DIM * DIM;
        const float* wv = SW_WV + (size_t)l * DIM * DIM;
        const float* wo = SW_WO + (size_t)l * DIM * DIM;
        const float* bo = SW_BO + (size_t)l * DIM;
        const float* w1 = SW_W1 + (size_t)l * MLP_H * DIM;
        const float* b1 = SW_B1 + (size_t)l * MLP_H;
        const float* w2 = SW_W2 + (size_t)l * DIM * MLP_H;
        const float* b2 = SW_B2 + (size_t)l * DIM;

        ln_kernel<<<T1, 128, 0, stream>>>(xa, SW_LN1G + l * DIM, SW_LN1B + l * DIM, xn);
        gemm_qkv_kernel<<<gQ1, 256, 0, stream>>>(xn, wq, wk, wv, qb, kb, vb, T1);
        attn_kernel<<<gA1, 256, 0, stream>>>(qb, kb, vb, rel, MSK, ab, N1, (l == 0) ? 1 : 0);
        gemm_kernel<<<gP1, 256, 0, stream>>>(ab, wo, bo, xa, nullptr, xa, T1, DIM, DIM, 0);
        ln_kernel<<<T1, 128, 0, stream>>>(xa, SW_LN2G + l * DIM, SW_LN2B + l * DIM, xn);
        gemm_kernel<<<gM1, 256, 0, stream>>>(xn, w1, b1, nullptr, nullptr, hb, T1, MLP_H, DIM, 1);
        gemm_kernel<<<gP1, 256, 0, stream>>>(hb, w2, b2, xa, nullptr, xa, T1, DIM, MLP_H, 0);
    }

    // ---------------- concat cls ----------------
    concat_kernel<<<(BATCH * N2 * DIM + 255) / 256, 256, 0, stream>>>(xa, CLSW, MSK, xb, m2);

    // ---------------- phase 2: bl layers (N=257) ----------------
    int MB2 = (T2 + 63) / 64;
    dim3 gP2(DIM / 64, MB2);
    dim3 gQ2(18, MB2);
    dim3 gM2(MLP_H / 64, MB2);
    dim3 gA2((N2 + 15) / 16, HEADS, BATCH);
    for (int l = 0; l < 12; l++) {
        const float* wq = BL_WQ + (size_t)l * DIM * DIM;
        const float* wk = BL_WK + (size_t)l * DIM * DIM;
        const float* wv = BL_WV + (size_t)l * DIM * DIM;
        const float* wo = BL_WO + (size_t)l * DIM * DIM;
        const float* bo = BL_BO + (size_t)l * DIM;
        const float* w1 = BL_W1 + (size_t)l * MLP_H * DIM;
        const float* b1 = BL_B1 + (size_t)l * MLP_H;
        const float* w2 = BL_W2 + (size_t)l * DIM * MLP_H;
        const float* b2 = BL_B2 + (size_t)l * DIM;
        const float* g1 = BL_G1 + (size_t)l * DIM;
        const float* g2 = BL_G2 + (size_t)l * DIM;

        ln_kernel<<<T2, 128, 0, stream>>>(xb, BL_LN1G + l * DIM, BL_LN1B + l * DIM, xn);
        gemm_qkv_kernel<<<gQ2, 256, 0, stream>>>(xn, wq, wk, wv, qb, kb, vb, T2);
        attn_kernel<<<gA2, 256, 0, stream>>>(qb, kb, vb, nullptr, m2, ab, N2, 0);
        gemm_kernel<<<gP2, 256, 0, stream>>>(ab, wo, bo, xb, g1, xb, T2, DIM, DIM, 0);
        ln_kernel<<<T2, 128, 0, stream>>>(xb, BL_LN2G + l * DIM, BL_LN2B + l * DIM, xn);
        gemm_kernel<<<gM2, 256, 0, stream>>>(xn, w1, b1, nullptr, nullptr, hb, T2, MLP_H, DIM, 1);
        gemm_kernel<<<gP2, 256, 0, stream>>>(hb, w2, b2, xb, g2, xb, T2, DIM, MLP_H, 0);
    }

    // ---------------- head ----------------
    head_kernel<<<BATCH * 3, 64, 0, stream>>>(xb, OUTW, OUTB, (float*)d_out);
}

// Round 3
// 5321.151 us; speedup vs baseline: 1.4809x; 1.0058x over previous
//
#include <hip/hip_runtime.h>
#include <hip/hip_bf16.h>
#include <math.h>

#define DIM 384
#define HEADS 12
#define HD 32
#define MLP_H 1536
#define BATCH 8
#define N1 256
#define N2 257
#define SCALE 0.17677669529663687f
#define TIME_SCALE 18.0f

// ------------------------------------------------------------------
// rel bias: rel[b,i,j,c] = sin_emb(1024*clip(d,-4,4))[k] @ wp[c,k] + bp[c]
// ------------------------------------------------------------------
__global__ __launch_bounds__(256) void rel_kernel(
        const float* __restrict__ x0, const float* __restrict__ w1d,
        const float* __restrict__ b1d, const float* __restrict__ wp,
        const float* __restrict__ bp, float* __restrict__ rel) {
    __shared__ float swp[HD * HD];
    __shared__ float sbp[HD];
    __shared__ float sw1[8];
    __shared__ float sb1;
    __shared__ float sfreq[16];
    int tid = threadIdx.x;
    for (int i = tid; i < HD * HD; i += 256) swp[i] = wp[i];
    if (tid < HD) sbp[tid] = bp[tid];
    if (tid < 8) sw1[tid] = w1d[tid];
    if (tid == 0) sb1 = b1d[0];
    if (tid < 16) sfreq[tid] = expf(-(float)tid * 0.5756462732485114f);
    __syncthreads();

    int gid = blockIdx.x * 256 + tid;
    int j  = gid & (N1 - 1);
    int bi = gid >> 8;
    int i  = bi & (N1 - 1);
    int b  = bi >> 8;

    const float* pi = x0 + (size_t)(b * N1 + i) * 4;
    const float* pj = x0 + (size_t)(b * N1 + j) * 4;
    float dx = pi[0] - pj[0], dy = pi[1] - pj[1], dz = pi[2] - pj[2];
    float dt = pi[3] - pj[3] * TIME_SCALE;
    float dx2 = dx * dx, dy2 = dy * dy, dz2 = dz * dz, dt2 = dt * dt;
    float ds2 = dx2 + dy2 + dz2 - dt2;
    float d = copysignf(sqrtf(fabsf(ds2)), ds2);
    d += dx * sw1[0] + dy * sw1[1] + dz * sw1[2] + dt * sw1[3]
       + dx2 * sw1[4] + dy2 * sw1[5] + dz2 * sw1[6] + dt2 * sw1[7] + sb1;
    d = fminf(fmaxf(d, -4.f), 4.f) * 1024.f;

    float emb[32];
    #pragma unroll
    for (int k = 0; k < 16; k++) {
        float s, c;
        sincosf(d * sfreq[k], &s, &c);
        emb[k] = s; emb[16 + k] = c;
    }
    float* out = rel + (size_t)gid * HD;
    #pragma unroll 4
    for (int c = 0; c < HD; c++) {
        float a = sbp[c];
        #pragma unroll
        for (int k = 0; k < 32; k++) a += emb[k] * swp[c * 32 + k];
        out[c] = a;
    }
}

// ------------------------------------------------------------------
// LayerNorm
// ------------------------------------------------------------------
__global__ __launch_bounds__(128) void ln_kernel(
        const float* __restrict__ x, const float* __restrict__ g,
        const float* __restrict__ b, float* __restrict__ y) {
    int r = blockIdx.x;
    int t = threadIdx.x;
    const float* xr = x + (size_t)r * DIM;
    float v0 = xr[t], v1 = xr[t + 128], v2 = xr[t + 256];
    __shared__ float redm[2], redv[2];
    float s = v0 + v1 + v2;
    for (int o = 32; o; o >>= 1) s += __shfl_down(s, o, 64);
    int lane = t & 63, wid = t >> 6;
    if (!lane) redm[wid] = s;
    __syncthreads();
    float mean = (redm[0] + redm[1]) * (1.f / DIM);
    float d0 = v0 - mean, d1 = v1 - mean, d2 = v2 - mean;
    float s2 = d0 * d0 + d1 * d1 + d2 * d2;
    for (int o = 32; o; o >>= 1) s2 += __shfl_down(s2, o, 64);
    if (!lane) redv[wid] = s2;
    __syncthreads();
    float var = (redv[0] + redv[1]) * (1.f / DIM);
    float rs = rsqrtf(var + 1e-5f);
    float* yr = y + (size_t)r * DIM;
    yr[t]       = d0 * rs * g[t]       + b[t];
    yr[t + 128] = d1 * rs * g[t + 128] + b[t + 128];
    yr[t + 256] = d2 * rs * g[t + 256] + b[t + 256];
}

// ------------------------------------------------------------------
// Generic GEMM (64x64 tile): C = act(A.W^T + bias), opt resid+gate
// ------------------------------------------------------------------
__global__ __launch_bounds__(256) void gemm_kernel(
        const float* __restrict__ A, const float* __restrict__ W,
        const float* __restrict__ bias, const float* __restrict__ resid,
        const float* __restrict__ gvec, float* __restrict__ C,
        int M, int Nn, int K, int do_gelu) {
    __shared__ float As[64][20];
    __shared__ float Ws[64][20];
    int tid = threadIdx.x;
    int n0 = blockIdx.x * 64;
    int m0 = blockIdx.y * 64;
    int tx = tid & 15, ty = tid >> 4;
    int lrow = tid >> 2, lcol = (tid & 3) * 4;

    float acc[4][4];
    #pragma unroll
    for (int a = 0; a < 4; a++)
        #pragma unroll
        for (int bb = 0; bb < 4; bb++) acc[a][bb] = 0.f;

    for (int k0 = 0; k0 < K; k0 += 16) {
        int am = m0 + lrow;
        float4 av = make_float4(0.f, 0.f, 0.f, 0.f);
        if (am < M) av = *(const float4*)(A + (size_t)am * K + k0 + lcol);
        As[lrow][lcol] = av.x; As[lrow][lcol + 1] = av.y;
        As[lrow][lcol + 2] = av.z; As[lrow][lcol + 3] = av.w;
        float4 wv = *(const float4*)(W + (size_t)(n0 + lrow) * K + k0 + lcol);
        Ws[lrow][lcol] = wv.x; Ws[lrow][lcol + 1] = wv.y;
        Ws[lrow][lcol + 2] = wv.z; Ws[lrow][lcol + 3] = wv.w;
        __syncthreads();
        #pragma unroll
        for (int k = 0; k < 16; k += 4) {
            float4 ra[4], rb[4];
            #pragma unroll
            for (int a = 0; a < 4; a++) ra[a] = *(const float4*)&As[ty + 16 * a][k];
            #pragma unroll
            for (int bb = 0; bb < 4; bb++) rb[bb] = *(const float4*)&Ws[tx + 16 * bb][k];
            #pragma unroll
            for (int a = 0; a < 4; a++)
                #pragma unroll
                for (int bb = 0; bb < 4; bb++)
                    acc[a][bb] += ra[a].x * rb[bb].x + ra[a].y * rb[bb].y
                                + ra[a].z * rb[bb].z + ra[a].w * rb[bb].w;
        }
        __syncthreads();
    }
    #pragma unroll
    for (int a = 0; a < 4; a++) {
        int m = m0 + ty + 16 * a;
        if (m >= M) continue;
        #pragma unroll
        for (int bb = 0; bb < 4; bb++) {
            int n = n0 + tx + 16 * bb;
            float v = acc[a][bb];
            if (bias) v += bias[n];
            if (do_gelu) v = 0.5f * v * (1.f + erff(v * 0.70710678118654752f));
            if (resid) {
                float gs = gvec ? gvec[n] : 1.f;
                v = resid[(size_t)m * Nn + n] + gs * v;
            }
            C[(size_t)m * Nn + n] = v;
        }
    }
}

// ------------------------------------------------------------------
// Fused QKV projection: same A, three weight matrices (384x384 each)
// ------------------------------------------------------------------
__global__ __launch_bounds__(256) void gemm_qkv_kernel(
        const float* __restrict__ A, const float* __restrict__ Wq,
        const float* __restrict__ Wk, const float* __restrict__ Wv,
        float* __restrict__ Oq, float* __restrict__ Ok, float* __restrict__ Ov,
        int M) {
    __shared__ float As[64][20];
    __shared__ float Ws[64][20];
    int tid = threadIdx.x;
    int nb = blockIdx.x;                 // 0..17
    int which = nb / 6;
    int n0 = (nb % 6) * 64;
    const float* W = (which == 0) ? Wq : (which == 1) ? Wk : Wv;
    float* C = (which == 0) ? Oq : (which == 1) ? Ok : Ov;
    int m0 = blockIdx.y * 64;
    int tx = tid & 15, ty = tid >> 4;
    int lrow = tid >> 2, lcol = (tid & 3) * 4;

    float acc[4][4];
    #pragma unroll
    for (int a = 0; a < 4; a++)
        #pragma unroll
        for (int bb = 0; bb < 4; bb++) acc[a][bb] = 0.f;

    for (int k0 = 0; k0 < DIM; k0 += 16) {
        int am = m0 + lrow;
        float4 av = make_float4(0.f, 0.f, 0.f, 0.f);
        if (am < M) av = *(const float4*)(A + (size_t)am * DIM + k0 + lcol);
        As[lrow][lcol] = av.x; As[lrow][lcol + 1] = av.y;
        As[lrow][lcol + 2] = av.z; As[lrow][lcol + 3] = av.w;
        float4 wv = *(const float4*)(W + (size_t)(n0 + lrow) * DIM + k0 + lcol);
        Ws[lrow][lcol] = wv.x; Ws[lrow][lcol + 1] = wv.y;
        Ws[lrow][lcol + 2] = wv.z; Ws[lrow][lcol + 3] = wv.w;
        __syncthreads();
        #pragma unroll
        for (int k = 0; k < 16; k += 4) {
            float4 ra[4], rb[4];
            #pragma unroll
            for (int a = 0; a < 4; a++) ra[a] = *(const float4*)&As[ty + 16 * a][k];
            #pragma unroll
            for (int bb = 0; bb < 4; bb++) rb[bb] = *(const float4*)&Ws[tx + 16 * bb][k];
            #pragma unroll
            for (int a = 0; a < 4; a++)
                #pragma unroll
                for (int bb = 0; bb < 4; bb++)
                    acc[a][bb] += ra[a].x * rb[bb].x + ra[a].y * rb[bb].y
                                + ra[a].z * rb[bb].z + ra[a].w * rb[bb].w;
        }
        __syncthreads();
    }
    #pragma unroll
    for (int a = 0; a < 4; a++) {
        int m = m0 + ty + 16 * a;
        if (m >= M) continue;
        #pragma unroll
        for (int bb = 0; bb < 4; bb++) {
            int n = n0 + tx + 16 * bb;
            C[(size_t)m * DIM + n] = acc[a][bb];
        }
    }
}

// ------------------------------------------------------------------
// Attention v3: block = (h, b, 32-query chunk), 512 threads (8 waves).
// Grid ordered (h, b, chunk) so all chunks of one (b,h) map to the same
// XCD (linear id % 8 is chunk-invariant) -> K/V re-reads hit that XCD L2.
// Wave w handles queries 4w..4w+3. K staged transposed (pitch 260),
// scores in LDS, V staged row-major (pitch 33).
// ------------------------------------------------------------------
#define KVP 260
#define VP 33
__global__ __launch_bounds__(512) void attn_kernel(
        const float* __restrict__ qb, const float* __restrict__ kb,
        const float* __restrict__ vb, const float* __restrict__ relb,
        const float* __restrict__ maskv, float* __restrict__ ob,
        int Nseq, int use_rel) {
    __shared__ float kvbuf[8580];     // max(32*260, 260*33)
    __shared__ float sc[32][260];
    __shared__ float qs4[32][32];     // [c][qq]
    __shared__ float qsT[32][32];     // [qq][c]
    __shared__ float ms[288];

    int tid = threadIdx.x;
    int w = tid >> 6, l = tid & 63;
    int h = blockIdx.x, b = blockIdx.y, chunk = blockIdx.z;
    int i0 = chunk * 32;
    size_t baseBH = (size_t)(b * Nseq) * DIM + h * HD;

    // ---- stage mask (padded with 0) ----
    for (int j = tid; j < 288; j += 512)
        ms[j] = (j < Nseq) ? maskv[b * Nseq + j] : 0.f;

    // ---- init sc tail columns 256..259 ----
    if (tid < 128) sc[tid >> 2][256 + (tid & 3)] = -3.0e38f;

    // ---- stage q (both layouts) ----
    for (int t = tid; t < 1024; t += 512) {
        int qq = t >> 5, c = t & 31;
        int i = i0 + qq;
        float v = 0.f;
        if (i < Nseq) v = qb[baseBH + (size_t)i * DIM + c] * SCALE;
        qs4[c][qq] = v;
        qsT[qq][c] = v;
    }

    // ---- stage K transposed: kvbuf[c*KVP + j]; 8 lanes cover a row ----
    {
        int q4 = tid & 7, r = tid >> 3;
        for (int j = r; j < Nseq; j += 64) {
            float4 kvv = *(const float4*)(kb + baseBH + (size_t)j * DIM + q4 * 4);
            kvbuf[(4 * q4 + 0) * KVP + j] = kvv.x;
            kvbuf[(4 * q4 + 1) * KVP + j] = kvv.y;
            kvbuf[(4 * q4 + 2) * KVP + j] = kvv.z;
            kvbuf[(4 * q4 + 3) * KVP + j] = kvv.w;
        }
        if (tid < 128) {
            int cc = tid >> 2, jj = 256 + (tid & 3);
            if (jj >= Nseq) kvbuf[cc * KVP + jj] = 0.f;
        }
    }
    __syncthreads();

    // ---- scores: wave w -> queries 4w..4w+3, lane l -> j=4l..4l+3 ----
    {
        float s[4][4];
        #pragma unroll
        for (int q = 0; q < 4; q++)
            #pragma unroll
            for (int t = 0; t < 4; t++) s[q][t] = 0.f;
        int j0 = 4 * l;
        #pragma unroll 8
        for (int c = 0; c < 32; c++) {
            float4 kq = *(const float4*)&kvbuf[c * KVP + j0];
            float4 q4 = *(const float4*)&qs4[c][4 * w];
            s[0][0] += q4.x * kq.x; s[0][1] += q4.x * kq.y; s[0][2] += q4.x * kq.z; s[0][3] += q4.x * kq.w;
            s[1][0] += q4.y * kq.x; s[1][1] += q4.y * kq.y; s[1][2] += q4.y * kq.z; s[1][3] += q4.y * kq.w;
            s[2][0] += q4.z * kq.x; s[2][1] += q4.z * kq.y; s[2][2] += q4.z * kq.z; s[2][3] += q4.z * kq.w;
            s[3][0] += q4.w * kq.x; s[3][1] += q4.w * kq.y; s[3][2] += q4.w * kq.z; s[3][3] += q4.w * kq.w;
        }
        if (use_rel) {                      // Nseq == 256 here, all i valid
            #pragma unroll
            for (int q = 0; q < 4; q++) {
                int i = i0 + 4 * w + q;
                float qr[32];
                #pragma unroll
                for (int c4 = 0; c4 < 8; c4++) {
                    float4 t4 = *(const float4*)&qsT[4 * w + q][c4 * 4];
                    qr[4 * c4] = t4.x; qr[4 * c4 + 1] = t4.y;
                    qr[4 * c4 + 2] = t4.z; qr[4 * c4 + 3] = t4.w;
                }
                const float* rbase = relb + (((size_t)b * N1 + i) * N1 + j0) * HD;
                #pragma unroll
                for (int jj = 0; jj < 4; jj++) {
                    float a = 0.f;
                    #pragma unroll
                    for (int c4 = 0; c4 < 8; c4++) {
                        float4 rv = *(const float4*)(rbase + jj * HD + c4 * 4);
                        a += qr[4 * c4] * rv.x + qr[4 * c4 + 1] * rv.y
                           + qr[4 * c4 + 2] * rv.z + qr[4 * c4 + 3] * rv.w;
                    }
                    s[q][jj] += a;
                }
            }
        }
        // mask bias + write scores
        #pragma unroll
        for (int q = 0; q < 4; q++) {
            int i = i0 + 4 * w + q;
            float mi = ms[i];
            float4 o4;
            float mj, mn, mx;
            mj = ms[j0 + 0]; mn = fminf(mi, mj); mx = fmaxf(mi, mj);
            o4.x = s[q][0] + ((mx < 0.f) ? 0.f : mn);
            mj = ms[j0 + 1]; mn = fminf(mi, mj); mx = fmaxf(mi, mj);
            o4.y = s[q][1] + ((mx < 0.f) ? 0.f : mn);
            mj = ms[j0 + 2]; mn = fminf(mi, mj); mx = fmaxf(mi, mj);
            o4.z = s[q][2] + ((mx < 0.f) ? 0.f : mn);
            mj = ms[j0 + 3]; mn = fminf(mi, mj); mx = fmaxf(mi, mj);
            o4.w = s[q][3] + ((mx < 0.f) ? 0.f : mn);
            *(float4*)&sc[4 * w + q][j0] = o4;
        }
        // tail column j = 256 (Nseq == 257): split reduction over c
        if (Nseq > 256) {
            int c = l & 31, h2 = l >> 5;
            float k256 = kvbuf[c * KVP + 256];
            float pa = qs4[c][4 * w + 2 * h2]     * k256;
            float pb = qs4[c][4 * w + 2 * h2 + 1] * k256;
            #pragma unroll
            for (int o = 16; o; o >>= 1) {
                pa += __shfl_xor(pa, o, 32);
                pb += __shfl_xor(pb, o, 32);
            }
            if ((l & 31) == 0) {
                int qa = 4 * w + 2 * h2, ia = i0 + qa;
                float mj = ms[256];
                float mia = ms[ia], mib = ms[ia + 1];
                sc[qa][256]     = pa + ((fmaxf(mia, mj) < 0.f) ? 0.f : fminf(mia, mj));
                sc[qa + 1][256] = pb + ((fmaxf(mib, mj) < 0.f) ? 0.f : fminf(mib, mj));
            }
        }
    }
    __syncthreads();

    // ---- stage V row-major: kvbuf[j*VP + c] ----
    {
        int q4 = tid & 7, r = tid >> 3;
        for (int j = r; j < Nseq; j += 64) {
            float4 vv = *(const float4*)(vb + baseBH + (size_t)j * DIM + q4 * 4);
            kvbuf[j * VP + 4 * q4 + 0] = vv.x;
            kvbuf[j * VP + 4 * q4 + 1] = vv.y;
            kvbuf[j * VP + 4 * q4 + 2] = vv.z;
            kvbuf[j * VP + 4 * q4 + 3] = vv.w;
        }
        for (int t = tid; t < 132; t += 512) {
            int row = 256 + t / VP, cc = t % VP;
            if (row < 260 && row >= Nseq) kvbuf[row * VP + cc] = 0.f;
        }
    }
    __syncthreads();

    // ---- softmax (per wave, per query) ----
    float inv[4];
    #pragma unroll
    for (int q = 0; q < 4; q++) {
        int qq = 4 * w + q;
        float4 sv = *(const float4*)&sc[qq][4 * l];
        float lm = fmaxf(fmaxf(sv.x, sv.y), fmaxf(sv.z, sv.w));
        float s256 = -3.0e38f;
        if (Nseq > 256) s256 = sc[qq][256];
        lm = fmaxf(lm, s256);
        #pragma unroll
        for (int o = 32; o; o >>= 1) lm = fmaxf(lm, __shfl_xor(lm, o, 64));
        float4 ev;
        ev.x = expf(sv.x - lm); ev.y = expf(sv.y - lm);
        ev.z = expf(sv.z - lm); ev.w = expf(sv.w - lm);
        float ls = ev.x + ev.y + ev.z + ev.w;
        #pragma unroll
        for (int o = 32; o; o >>= 1) ls += __shfl_xor(ls, o, 64);
        if (Nseq > 256) {
            float e256 = expf(s256 - lm);
            ls += e256;
            if (l == 0) {
                float4 t4; t4.x = e256; t4.y = 0.f; t4.z = 0.f; t4.w = 0.f;
                *(float4*)&sc[qq][256] = t4;
            }
        }
        *(float4*)&sc[qq][4 * l] = ev;
        inv[q] = 1.f / ls;
    }
    __syncthreads();

    // ---- PV: role switch, lane = (c, h2); j interleaved quads ----
    {
        int c = l & 31, h2 = l >> 5;
        float acc[4] = {0.f, 0.f, 0.f, 0.f};
        int JMAX = (Nseq > 256) ? 260 : 256;
        for (int j0 = 4 * h2; j0 < JMAX; j0 += 8) {
            float v0 = kvbuf[(j0 + 0) * VP + c];
            float v1 = kvbuf[(j0 + 1) * VP + c];
            float v2 = kvbuf[(j0 + 2) * VP + c];
            float v3 = kvbuf[(j0 + 3) * VP + c];
            #pragma unroll
            for (int q = 0; q < 4; q++) {
                float4 pv = *(const float4*)&sc[4 * w + q][j0];
                acc[q] += pv.x * v0 + pv.y * v1 + pv.z * v2 + pv.w * v3;
                if (use_rel) {
                    int i = i0 + 4 * w + q;
                    const float* rr = relb + (((size_t)b * N1 + i) * N1 + j0) * HD + c;
                    acc[q] += pv.x * rr[0] + pv.y * rr[HD] + pv.z * rr[2 * HD] + pv.w * rr[3 * HD];
                }
            }
        }
        #pragma unroll
        for (int q = 0; q < 4; q++) {
            float t = __shfl_down(acc[q], 32, 64);
            acc[q] += t;
        }
        if (l < 32) {
            #pragma unroll
            for (int q = 0; q < 4; q++) {
                int i = i0 + 4 * w + q;
                if (i < Nseq) ob[baseBH + (size_t)i * DIM + c] = acc[q] * inv[q];
            }
        }
    }
}

// ------------------------------------------------------------------
__global__ __launch_bounds__(256) void concat_kernel(
        const float* __restrict__ xa, const float* __restrict__ clsw,
        const float* __restrict__ mask, float* __restrict__ xb,
        float* __restrict__ m2) {
    int idx = blockIdx.x * 256 + threadIdx.x;
    const int total = BATCH * N2 * DIM;
    if (idx < total) {
        int c = idx % DIM;
        int tokb = idx / DIM;
        int p = tokb % N2, b = tokb / N2;
        xb[idx] = (p == 0) ? clsw[c] : xa[((size_t)(b * N1) + p - 1) * DIM + c];
    }
    if (idx < BATCH * N2) {
        int p = idx % N2, b = idx / N2;
        m2[idx] = (p == 0) ? 0.f : mask[b * N1 + p - 1];
    }
}

__global__ __launch_bounds__(64) void head_kernel(
        const float* __restrict__ xb, const float* __restrict__ ow,
        const float* __restrict__ obv, float* __restrict__ out) {
    int blk = blockIdx.x;
    int b = blk / 3, o = blk % 3;
    int lane = threadIdx.x;
    const float* xr = xb + (size_t)(b * N2) * DIM;
    const float* wr = ow + o * DIM;
    float s = 0.f;
    for (int c = lane; c < DIM; c += 64) s += xr[c] * wr[c];
    for (int off = 32; off; off >>= 1) s += __shfl_down(s, off, 64);
    if (!lane) out[blk] = s + obv[o];
}

// ------------------------------------------------------------------
extern "C" void kernel_launch(void* const* d_in, const int* in_sizes, int n_in,
                              void* d_out, int out_size, void* d_ws, size_t ws_size,
                              hipStream_t stream) {
    (void)in_sizes; (void)n_in; (void)out_size; (void)ws_size;
    const float* X       = (const float*)d_in[0];
    const float* X0      = (const float*)d_in[1];
    const float* MSK     = (const float*)d_in[2];
    const float* RW1     = (const float*)d_in[3];
    const float* RB1     = (const float*)d_in[4];
    const float* RWP     = (const float*)d_in[5];
    const float* RBP     = (const float*)d_in[6];
    const float* SW_LN1G = (const float*)d_in[7];
    const float* SW_LN1B = (const float*)d_in[8];
    const float* SW_LN2G = (const float*)d_in[9];
    const float* SW_LN2B = (const float*)d_in[10];
    const float* SW_WQ   = (const float*)d_in[11];
    const float* SW_WK   = (const float*)d_in[12];
    const float* SW_WV   = (const float*)d_in[13];
    const float* SW_WO   = (const float*)d_in[14];
    const float* SW_BO   = (const float*)d_in[15];
    const float* SW_W1   = (const float*)d_in[16];
    const float* SW_B1   = (const float*)d_in[17];
    const float* SW_W2   = (const float*)d_in[18];
    const float* SW_B2   = (const float*)d_in[19];
    const float* BL_LN1G = (const float*)d_in[20];
    const float* BL_LN1B = (const float*)d_in[21];
    const float* BL_LN2G = (const float*)d_in[22];
    const float* BL_LN2B = (const float*)d_in[23];
    const float* BL_WQ   = (const float*)d_in[24];
    const float* BL_WK   = (const float*)d_in[25];
    const float* BL_WV   = (const float*)d_in[26];
    const float* BL_WO   = (const float*)d_in[27];
    const float* BL_BO   = (const float*)d_in[28];
    const float* BL_W1   = (const float*)d_in[29];
    const float* BL_B1   = (const float*)d_in[30];
    const float* BL_W2   = (const float*)d_in[31];
    const float* BL_B2   = (const float*)d_in[32];
    const float* BL_G1   = (const float*)d_in[33];
    const float* BL_G2   = (const float*)d_in[34];
    const float* CLSW    = (const float*)d_in[35];
    const float* OUTW    = (const float*)d_in[36];
    const float* OUTB    = (const float*)d_in[37];

    const int T1 = BATCH * N1;   // 2048
    const int T2 = BATCH * N2;   // 2056
    const size_t ROWS = (size_t)T2 * DIM;
    const size_t RELSZ = (size_t)BATCH * N1 * N1 * HD;

    float* ws  = (float*)d_ws;
    float* rel = ws;
    float* xa  = rel + RELSZ;
    float* xb  = xa + ROWS;
    float* xn  = xb + ROWS;
    float* qb  = xn + ROWS;
    float* kb  = qb + ROWS;
    float* vb  = kb + ROWS;
    float* ab  = vb + ROWS;
    float* hb  = ab + ROWS;
    float* m2  = hb + (size_t)T2 * MLP_H;

    rel_kernel<<<BATCH * N1 * N1 / 256, 256, 0, stream>>>(X0, RW1, RB1, RWP, RBP, rel);
    hipMemcpyAsync(xa, X, sizeof(float) * T1 * DIM, hipMemcpyDeviceToDevice, stream);

    // ---------------- phase 1: sw layers (N=256) ----------------
    dim3 gP1(DIM / 64, T1 / 64);
    dim3 gQ1(18, T1 / 64);
    dim3 gM1(MLP_H / 64, T1 / 64);
    dim3 gA1(HEADS, BATCH, N1 / 32);            // (12,8,8) XCD-local chunks
    for (int l = 0; l < 4; l++) {
        const float* wq = SW_WQ + (size_t)l * DIM * DIM;
        const float* wk = SW_WK + (size_t)l * DIM * DIM;
        const float* wv = SW_WV + (size_t)l * DIM * DIM;
        const float* wo = SW_WO + (size_t)l * DIM * DIM;
        const float* bo = SW_BO + (size_t)l * DIM;
        const float* w1 = SW_W1 + (size_t)l * MLP_H * DIM;
        const float* b1 = SW_B1 + (size_t)l * MLP_H;
        const float* w2 = SW_W2 + (size_t)l * DIM * MLP_H;
        const float* b2 = SW_B2 + (size_t)l * DIM;

        ln_kernel<<<T1, 128, 0, stream>>>(xa, SW_LN1G + l * DIM, SW_LN1B + l * DIM, xn);
        gemm_qkv_kernel<<<gQ1, 256, 0, stream>>>(xn, wq, wk, wv, qb, kb, vb, T1);
        attn_kernel<<<gA1, 512, 0, stream>>>(qb, kb, vb, rel, MSK, ab, N1, (l == 0) ? 1 : 0);
        gemm_kernel<<<gP1, 256, 0, stream>>>(ab, wo, bo, xa, nullptr, xa, T1, DIM, DIM, 0);
        ln_kernel<<<T1, 128, 0, stream>>>(xa, SW_LN2G + l * DIM, SW_LN2B + l * DIM, xn);
        gemm_kernel<<<gM1, 256, 0, stream>>>(xn, w1, b1, nullptr, nullptr, hb, T1, MLP_H, DIM, 1);
        gemm_kernel<<<gP1, 256, 0, stream>>>(hb, w2, b2, xa, nullptr, xa, T1, DIM, MLP_H, 0);
    }

    // ---------------- concat cls ----------------
    concat_kernel<<<(BATCH * N2 * DIM + 255) / 256, 256, 0, stream>>>(xa, CLSW, MSK, xb, m2);

    // ---------------- phase 2: bl layers (N=257) ----------------
    int MB2 = (T2 + 63) / 64;
    dim3 gP2(DIM / 64, MB2);
    dim3 gQ2(18, MB2);
    dim3 gM2(MLP_H / 64, MB2);
    dim3 gA2(HEADS, BATCH, (N2 + 31) / 32);     // (12,8,9)
    for (int l = 0; l < 12; l++) {
        const float* wq = BL_WQ + (size_t)l * DIM * DIM;
        const float* wk = BL_WK + (size_t)l * DIM * DIM;
        const float* wv = BL_WV + (size_t)l * DIM * DIM;
        const float* wo = BL_WO + (size_t)l * DIM * DIM;
        const float* bo = BL_BO + (size_t)l * DIM;
        const float* w1 = BL_W1 + (size_t)l * MLP_H * DIM;
        const float* b1 = BL_B1 + (size_t)l * MLP_H;
        const float* w2 = BL_W2 + (size_t)l * DIM * MLP_H;
        const float* b2 = BL_B2 + (size_t)l * DIM;
        const float* g1 = BL_G1 + (size_t)l * DIM;
        const float* g2 = BL_G2 + (size_t)l * DIM;

        ln_kernel<<<T2, 128, 0, stream>>>(xb, BL_LN1G + l * DIM, BL_LN1B + l * DIM, xn);
        gemm_qkv_kernel<<<gQ2, 256, 0, stream>>>(xn, wq, wk, wv, qb, kb, vb, T2);
        attn_kernel<<<gA2, 512, 0, stream>>>(qb, kb, vb, nullptr, m2, ab, N2, 0);
        gemm_kernel<<<gP2, 256, 0, stream>>>(ab, wo, bo, xb, g1, xb, T2, DIM, DIM, 0);
        ln_kernel<<<T2, 128, 0, stream>>>(xb, BL_LN2G + l * DIM, BL_LN2B + l * DIM, xn);
        gemm_kernel<<<gM2, 256, 0, stream>>>(xn, w1, b1, nullptr, nullptr, hb, T2, MLP_H, DIM, 1);
        gemm_kernel<<<gP2, 256, 0, stream>>>(hb, w2, b2, xb, g2, xb, T2, DIM, MLP_H, 0);
    }

    // ---------------- head ----------------
    head_kernel<<<BATCH * 3, 64, 0, stream>>>(xb, OUTW, OUTB, (float*)d_out);
}